// Round 3
// baseline (6263.035 us; speedup 1.0000x reference)
//
#include <hip/hip_runtime.h>
#include <cmath>

#define Bc 32
#define Tc 32
#define Sc 64
#define Hc 512
#define Ec 512
#define Vc 32000
#define NEGC (-1e9f)
#define BH (Bc * Hc)
#define Mtot ((Tc - 1) * Bc)   // 992
#define NBLK 256

__device__ __forceinline__ float sigf(float x) { return 1.0f / (1.0f + expf(-x)); }

__device__ __forceinline__ float dot4(const float* a, const float* b) {
    float4 x = *(const float4*)a;
    float4 y = *(const float4*)b;
    return x.x * y.x + x.y * y.y + x.z * y.z + x.w * y.w;
}

// Manual grid barrier (device scope). Monotonic counter in workspace, reset by
// k_proj each launch. All NBLK blocks co-resident (1 block/CU fits trivially),
// so the spin cannot deadlock. Release: __threadfence + agent-scope RMW.
// Acquire: relaxed agent-scope spin, then __threadfence before reading data.
__device__ __forceinline__ void gbar(unsigned int* cnt, unsigned int target) {
    __syncthreads();
    if (threadIdx.x == 0) {
        __threadfence();
        __hip_atomic_fetch_add(cnt, 1u, __ATOMIC_ACQ_REL, __HIP_MEMORY_SCOPE_AGENT);
        while (__hip_atomic_load(cnt, __ATOMIC_RELAXED, __HIP_MEMORY_SCOPE_AGENT) < target)
            __builtin_amdgcn_s_sleep(1);
        __threadfence();
    }
    __syncthreads();
}

// proj[b][s][k] = sum_h W_a[k][h] * enc[s][b][h]   (+ resets barrier counter)
__global__ __launch_bounds__(256) void k_proj(const float* __restrict__ W_a,
                                              const float* __restrict__ enc,
                                              float* __restrict__ proj,
                                              unsigned int* __restrict__ cnt) {
    if (blockIdx.x == 0 && blockIdx.y == 0 && blockIdx.z == 0 && threadIdx.x == 0)
        *cnt = 0u;   // visible to k_loop via kernel-boundary ordering
    int k = blockIdx.x * 256 + threadIdx.x;
    int s0 = blockIdx.y * 8;
    int b = blockIdx.z;
    __shared__ float se[8][Hc];
    for (int i = threadIdx.x; i < 8 * Hc; i += 256) {
        int ss = i >> 9, hh = i & (Hc - 1);
        se[ss][hh] = enc[((size_t)(s0 + ss) * Bc + b) * Hc + hh];
    }
    __syncthreads();
    const float* wr = W_a + (size_t)k * Hc;
    float acc[8];
#pragma unroll
    for (int ss = 0; ss < 8; ++ss) acc[ss] = 0.0f;
    for (int h = 0; h < Hc; h += 4) {
        float4 w = *(const float4*)(wr + h);
#pragma unroll
        for (int ss = 0; ss < 8; ++ss) {
            acc[ss] = fmaf(w.x, se[ss][h + 0], acc[ss]);
            acc[ss] = fmaf(w.y, se[ss][h + 1], acc[ss]);
            acc[ss] = fmaf(w.z, se[ss][h + 2], acc[ss]);
            acc[ss] = fmaf(w.w, se[ss][h + 3], acc[ss]);
        }
    }
#pragma unroll
    for (int ss = 0; ss < 8; ++ss)
        proj[((size_t)b * Sc + s0 + ss) * Hc + k] = acc[ss];
}

// Persistent decode loop, REGULAR launch (no cooperative API) + manual gbar.
// Per step, 2 grid barriers:
//   phase 1: gates GEMM + LSTM pointwise (all 256 blocks)   == k_step1 chains
//   phase 2/3/4: score+softmax+ctx+Wc (blocks 0..31, b=blk) == k_score/k_ctx/k_wc chains
// Every per-output fp chain is bit-identical to the verified round-0 version.
__global__ __launch_bounds__(256) void k_loop(
    const int* __restrict__ tgt, const int* __restrict__ len_src,
    const float* __restrict__ enc, const float* __restrict__ h0,
    const float* __restrict__ c0, const float* __restrict__ emb,
    const float* __restrict__ W_ih, const float* __restrict__ W_hh,
    const float* __restrict__ b_ih, const float* __restrict__ b_hh,
    const float* __restrict__ proj, const float* __restrict__ W_c,
    const float* __restrict__ b_c,
    float* __restrict__ hbuf, float* __restrict__ cbuf,
    float* __restrict__ ah_all, unsigned int* __restrict__ cnt) {
    int blk = blockIdx.x, tid = threadIdx.x;
    unsigned int gen = 0;

    // prologue == k_init
    {
        int i = blk * 256 + tid;
        if (i < BH) { hbuf[i] = h0[i]; cbuf[i] = c0[i]; ah_all[i] = 0.0f; }
    }
    gbar(cnt, ++gen * NBLK);

    __shared__ float sg[2][4][32];
    __shared__ __align__(16) float sh[Hc];    // h2 for this batch
    __shared__ __align__(16) float scv[Hc];   // ctx for this batch
    __shared__ float ss[Sc];
    __shared__ float sal[Sc];

    int cur = 0;
    for (int t = 0; t < Tc - 1; ++t) {
        int nxt = 1 - cur;
        const float* hP = hbuf + cur * BH;
        float*       hN = hbuf + nxt * BH;
        const float* cP = cbuf + cur * BH;
        float*       cN = cbuf + nxt * BH;
        const float* aP = ah_all + (size_t)t * BH;
        float*       aN = ah_all + (size_t)(t + 1) * BH;

        // ---------------- phase 1: k_step1 (all 256 blocks) ----------------
        {
            int b  = tid & 31;
            int q  = (tid >> 5) & 3;
            int hl = tid >> 7;
            int h  = blk * 2 + hl;
            int j  = q * Hc + h;
            int w  = tgt[b * Tc + t];
            const float* x  = emb + (size_t)w * Ec;
            const float* wi = W_ih + (size_t)j * (Ec + Hc);
            const float* wh = W_hh + (size_t)j * Hc;
            const float* ap = aP + b * Hc;
            const float* hp = hP + b * Hc;
            float a0 = 0.f, a1 = 0.f, a2 = 0.f, a3 = 0.f;
            for (int e = 0; e < Ec; e += 16) {
                a0 += dot4(x + e, wi + e);
                a1 += dot4(x + e + 4, wi + e + 4);
                a2 += dot4(x + e + 8, wi + e + 8);
                a3 += dot4(x + e + 12, wi + e + 12);
            }
            for (int k = 0; k < Hc; k += 16) {
                a0 += dot4(ap + k, wi + Ec + k);
                a1 += dot4(ap + k + 4, wi + Ec + k + 4);
                a2 += dot4(ap + k + 8, wi + Ec + k + 8);
                a3 += dot4(ap + k + 12, wi + Ec + k + 12);
            }
            for (int k = 0; k < Hc; k += 16) {
                a0 += dot4(hp + k, wh + k);
                a1 += dot4(hp + k + 4, wh + k + 4);
                a2 += dot4(hp + k + 8, wh + k + 8);
                a3 += dot4(hp + k + 12, wh + k + 12);
            }
            float acc = b_ih[j] + b_hh[j] + ((a0 + a1) + (a2 + a3));
            sg[hl][q][b] = acc;
            __syncthreads();
            if (q == 0) {
                float iv = sigf(sg[hl][0][b]);
                float fv = sigf(sg[hl][1][b]);
                float gv = tanhf(sg[hl][2][b]);
                float ov = sigf(sg[hl][3][b]);
                int idx = b * Hc + h;
                float c2 = fv * cP[idx] + iv * gv;
                float h2v = ov * tanhf(c2);
                cN[idx] = c2;
                hN[idx] = h2v;
            }
        }
        gbar(cnt, ++gen * NBLK);

        // ------- phase 2/3/4: k_score + k_ctx + k_wc (blocks 0..31) -------
        if (blk < Bc) {
            int b = blk;
            for (int k = tid; k < Hc; k += 256) sh[k] = hN[b * Hc + k];
            __syncthreads();
            // scores (k_score chain)
            {
                int s = tid >> 2, r = tid & 3;
                const float* pr = proj + ((size_t)b * Sc + s) * Hc + r * 128;
                const float* hh = sh + r * 128;
                float p0 = 0.f, p1 = 0.f;
                for (int k = 0; k < 128; k += 8) {
                    p0 += dot4(hh + k, pr + k);
                    p1 += dot4(hh + k + 4, pr + k + 4);
                }
                float p = p0 + p1;
                p += __shfl_xor(p, 1);
                p += __shfl_xor(p, 2);
                if (r == 0) ss[s] = p;
            }
            __syncthreads();
            // masked softmax (k_score chain), lanes 0..63 of wave 0
            if (tid < Sc) {
                int len = len_src[b];
                float sc = (tid < len) ? ss[tid] : NEGC;
                float mx = sc;
#pragma unroll
                for (int m = 32; m >= 1; m >>= 1) mx = fmaxf(mx, __shfl_xor(mx, m));
                float p = expf(sc - mx);
                float sum = p;
#pragma unroll
                for (int m = 32; m >= 1; m >>= 1) sum += __shfl_xor(sum, m);
                sal[tid] = p / sum;
            }
            __syncthreads();
            // ctx (k_ctx chain): per h, two 32-long serial chains + one add
#pragma unroll
            for (int rep = 0; rep < 2; ++rep) {
                int h = tid + rep * 256;
                float accA = 0.0f, accB = 0.0f;
                for (int s = 0; s < 32; ++s)
                    accA = fmaf(sal[s], enc[((size_t)s * Bc + b) * Hc + h], accA);
                for (int s = 32; s < 64; ++s)
                    accB = fmaf(sal[s], enc[((size_t)s * Bc + b) * Hc + h], accB);
                scv[h] = accA + accB;
            }
            __syncthreads();
            // Wc (k_wc chain): each thread does k = tid and k = tid+256
#pragma unroll
            for (int rep = 0; rep < 2; ++rep) {
                int k = tid + rep * 256;
                const float* wc = W_c + (size_t)k * (2 * Hc);
                float a0 = 0.f, a1 = 0.f, a2 = 0.f, a3 = 0.f;
                for (int j = 0; j < Hc; j += 16) {
                    a0 += dot4(sh + j, wc + j);
                    a1 += dot4(sh + j + 4, wc + j + 4);
                    a2 += dot4(sh + j + 8, wc + j + 8);
                    a3 += dot4(sh + j + 12, wc + j + 12);
                }
                const float* wc2 = wc + Hc;
                for (int j = 0; j < Hc; j += 16) {
                    a0 += dot4(scv + j, wc2 + j);
                    a1 += dot4(scv + j + 4, wc2 + j + 4);
                    a2 += dot4(scv + j + 8, wc2 + j + 8);
                    a3 += dot4(scv + j + 12, wc2 + j + 12);
                }
                aN[b * Hc + k] = tanhf(b_c[k] + ((a0 + a1) + (a2 + a3)));
            }
        }
        gbar(cnt, ++gen * NBLK);
        cur = nxt;
    }
}

// Batched logits GEMM: C[m][n] = A[m][:] . W_o[n][:] + b_o[n]
__global__ __launch_bounds__(256) void k_biglogits(const float* __restrict__ A,
                                                   const float* __restrict__ W_o,
                                                   const float* __restrict__ b_o,
                                                   float* __restrict__ out) {
    __shared__ float At[32][128];
    __shared__ float Bt[32][128];
    int tid = threadIdx.x;
    int n_base = blockIdx.x * 128;
    int m_base = blockIdx.y * 128;
    int tn = tid & 15, tm = tid >> 4;

    float acc[2][4][2][4];
#pragma unroll
    for (int mg = 0; mg < 2; ++mg)
#pragma unroll
        for (int mi = 0; mi < 4; ++mi)
#pragma unroll
            for (int ng = 0; ng < 2; ++ng)
#pragma unroll
                for (int ni = 0; ni < 4; ++ni) acc[mg][mi][ng][ni] = 0.0f;

    int srow = tid >> 1;
    int koff = (tid & 1) * 16;
    int gm = m_base + srow;
    const float* arow = A + (size_t)gm * Hc + koff;
    const float* brow = W_o + (size_t)(n_base + srow) * Hc + koff;

    for (int kc = 0; kc < Hc; kc += 32) {
        float av[16], bv[16];
#pragma unroll
        for (int i = 0; i < 4; ++i) {
            float4 t4 = (gm < Mtot) ? *(const float4*)(arow + kc + i * 4)
                                    : make_float4(0.f, 0.f, 0.f, 0.f);
            av[i * 4 + 0] = t4.x; av[i * 4 + 1] = t4.y; av[i * 4 + 2] = t4.z; av[i * 4 + 3] = t4.w;
            float4 u4 = *(const float4*)(brow + kc + i * 4);
            bv[i * 4 + 0] = u4.x; bv[i * 4 + 1] = u4.y; bv[i * 4 + 2] = u4.z; bv[i * 4 + 3] = u4.w;
        }
        __syncthreads();
#pragma unroll
        for (int i = 0; i < 16; ++i) {
            At[koff + i][srow] = av[i];
            Bt[koff + i][srow] = bv[i];
        }
        __syncthreads();
#pragma unroll
        for (int k = 0; k < 32; ++k) {
            float4 a0 = *(const float4*)&At[k][tm * 4];
            float4 a1 = *(const float4*)&At[k][64 + tm * 4];
            float4 b0 = *(const float4*)&Bt[k][tn * 4];
            float4 b1 = *(const float4*)&Bt[k][64 + tn * 4];
            float am[2][4] = {{a0.x, a0.y, a0.z, a0.w}, {a1.x, a1.y, a1.z, a1.w}};
            float bn[2][4] = {{b0.x, b0.y, b0.z, b0.w}, {b1.x, b1.y, b1.z, b1.w}};
#pragma unroll
            for (int mg = 0; mg < 2; ++mg)
#pragma unroll
                for (int mi = 0; mi < 4; ++mi)
#pragma unroll
                    for (int ng = 0; ng < 2; ++ng)
#pragma unroll
                        for (int ni = 0; ni < 4; ++ni)
                            acc[mg][mi][ng][ni] = fmaf(am[mg][mi], bn[ng][ni], acc[mg][mi][ng][ni]);
        }
        __syncthreads();
    }

#pragma unroll
    for (int ng = 0; ng < 2; ++ng) {
        int n = n_base + ng * 64 + tn * 4;
        float4 bo = *(const float4*)(b_o + n);
#pragma unroll
        for (int mg = 0; mg < 2; ++mg)
#pragma unroll
            for (int mi = 0; mi < 4; ++mi) {
                int m = m_base + mg * 64 + tm * 4 + mi;
                if (m < Mtot) {
                    float4 v;
                    v.x = acc[mg][mi][ng][0] + bo.x;
                    v.y = acc[mg][mi][ng][1] + bo.y;
                    v.z = acc[mg][mi][ng][2] + bo.z;
                    v.w = acc[mg][mi][ng][3] + bo.w;
                    *(float4*)(out + (size_t)m * Vc + n) = v;
                }
            }
    }
}

// Per row m: argmax (first tiebreak) + logsumexp, then subtract in place; words out.
__global__ __launch_bounds__(256) void k_reduce_norm(float* __restrict__ out,
                                                     float* __restrict__ words) {
    int m = blockIdx.x, tid = threadIdx.x;
    float* row = out + (size_t)m * Vc;
    float mx = -INFINITY;
    int mi = 0;
    for (int v = tid; v < Vc; v += 256) {
        float x = row[v];
        if (x > mx) { mx = x; mi = v; }
    }
    __shared__ float smx[256];
    __shared__ int smi[256];
    __shared__ float ssum[256];
    smx[tid] = mx; smi[tid] = mi;
    __syncthreads();
    for (int off = 128; off; off >>= 1) {
        if (tid < off) {
            float o = smx[tid + off]; int oi = smi[tid + off];
            if (o > smx[tid] || (o == smx[tid] && oi < smi[tid])) { smx[tid] = o; smi[tid] = oi; }
        }
        __syncthreads();
    }
    float gmx = smx[0];
    float s = 0.0f;
    for (int v = tid; v < Vc; v += 256) s += expf(row[v] - gmx);
    ssum[tid] = s;
    __syncthreads();
    for (int off = 128; off; off >>= 1) {
        if (tid < off) ssum[tid] += ssum[tid + off];
        __syncthreads();
    }
    float lse = gmx + logf(ssum[0]);
    __syncthreads();
    for (int v = tid; v < Vc; v += 256) row[v] -= lse;
    if (tid == 0) words[m] = (float)smi[0];
}

extern "C" void kernel_launch(void* const* d_in, const int* in_sizes, int n_in,
                              void* d_out, int out_size, void* d_ws, size_t ws_size,
                              hipStream_t stream) {
    const int*   tgt     = (const int*)d_in[0];
    const int*   len_src = (const int*)d_in[1];
    const float* enc     = (const float*)d_in[2];
    const float* h0      = (const float*)d_in[3];
    const float* c0      = (const float*)d_in[4];
    const float* emb     = (const float*)d_in[5];
    const float* W_ih    = (const float*)d_in[6];
    const float* W_hh    = (const float*)d_in[7];
    const float* b_ih    = (const float*)d_in[8];
    const float* b_hh    = (const float*)d_in[9];
    const float* W_a     = (const float*)d_in[10];
    const float* W_c     = (const float*)d_in[11];
    const float* b_c     = (const float*)d_in[12];
    const float* W_o     = (const float*)d_in[13];
    const float* b_o     = (const float*)d_in[14];

    float* out = (float*)d_out;
    float* ws = (float*)d_ws;

    float* proj   = ws;                          // B*S*H = 1,048,576
    float* hbuf   = proj + (size_t)Bc * Sc * Hc; // 2 * BH
    float* cbuf   = hbuf + 2 * BH;               // 2 * BH
    float* ah_all = cbuf + 2 * BH;               // 32 * BH (slot0 = zeros)
    unsigned int* cnt = (unsigned int*)(ah_all + 32 * BH);
    float* out_words = out + (size_t)(Tc - 1) * Bc * Vc;

    {
        dim3 g(Hc / 256, Sc / 8, Bc);
        k_proj<<<g, 256, 0, stream>>>(W_a, enc, proj, cnt);
    }

    k_loop<<<NBLK, 256, 0, stream>>>(tgt, len_src, enc, h0, c0, emb,
                                     W_ih, W_hh, b_ih, b_hh, proj, W_c, b_c,
                                     hbuf, cbuf, ah_all, cnt);

    {
        dim3 g(Vc / 128, (Mtot + 127) / 128);    // 250 x 8
        k_biglogits<<<g, 256, 0, stream>>>(ah_all + BH, W_o, b_o, out);
    }
    k_reduce_norm<<<Mtot, 256, 0, stream>>>(out, out_words);
}

// Round 4
// 5440.953 us; speedup vs baseline: 1.1511x; 1.1511x over previous
//
#include <hip/hip_runtime.h>
#include <cmath>

#define Bc 32
#define Tc 32
#define Sc 64
#define Hc 512
#define Ec 512
#define Vc 32000
#define NEGC (-1e9f)
#define BH (Bc * Hc)
#define Mtot ((Tc - 1) * Bc)   // 992
#define NBLK 256

__device__ __forceinline__ float sigf(float x) { return 1.0f / (1.0f + expf(-x)); }

__device__ __forceinline__ float dot4(const float* a, const float* b) {
    float4 x = *(const float4*)a;
    float4 y = *(const float4*)b;
    return x.x * y.x + x.y * y.y + x.z * y.z + x.w * y.w;
}

// Write-through store to the device coherence point (sc0/sc1). Used for all
// data that crosses a grid barrier, so the barrier needs NO cache flush/inv.
__device__ __forceinline__ void stg(float* p, float v) {
    __hip_atomic_store(p, v, __ATOMIC_RELAXED, __HIP_MEMORY_SCOPE_AGENT);
}

// Grid barrier with ZERO cache-maintenance instructions (the round-3 version's
// __threadfence() lowered to per-block buffer_wbl2+buffer_inv = serialized
// full-L2 walks; that was ~90us/barrier and blew away the weight cache).
// Correctness: (a) cross-barrier data is stored write-through (stg) and its
// addresses are write-once for the whole kernel (rotating buffers), so normal
// cached reads can never see stale lines; (b) each wave drains vmcnt before
// the barrier so through-stores are globally visible; (c) counter ops are
// agent-scope atomics (bypass L1/L2, execute at the coherent point).
__device__ __forceinline__ void gbar(unsigned int* cnt, unsigned int target) {
    asm volatile("s_waitcnt vmcnt(0)" ::: "memory");
    __syncthreads();
    if (threadIdx.x == 0) {
        __hip_atomic_fetch_add(cnt, 1u, __ATOMIC_RELAXED, __HIP_MEMORY_SCOPE_AGENT);
        while (__hip_atomic_load(cnt, __ATOMIC_RELAXED, __HIP_MEMORY_SCOPE_AGENT) < target)
            __builtin_amdgcn_s_sleep(2);
    }
    __syncthreads();
    asm volatile("" ::: "memory");
}

// proj[b][s][k] = sum_h W_a[k][h] * enc[s][b][h]   (+ resets barrier counter)
__global__ __launch_bounds__(256) void k_proj(const float* __restrict__ W_a,
                                              const float* __restrict__ enc,
                                              float* __restrict__ proj,
                                              unsigned int* __restrict__ cnt) {
    if (blockIdx.x == 0 && blockIdx.y == 0 && blockIdx.z == 0 && threadIdx.x == 0)
        *cnt = 0u;   // visible to k_loop via kernel-boundary release
    int k = blockIdx.x * 256 + threadIdx.x;
    int s0 = blockIdx.y * 8;
    int b = blockIdx.z;
    __shared__ float se[8][Hc];
    for (int i = threadIdx.x; i < 8 * Hc; i += 256) {
        int ss = i >> 9, hh = i & (Hc - 1);
        se[ss][hh] = enc[((size_t)(s0 + ss) * Bc + b) * Hc + hh];
    }
    __syncthreads();
    const float* wr = W_a + (size_t)k * Hc;
    float acc[8];
#pragma unroll
    for (int ss = 0; ss < 8; ++ss) acc[ss] = 0.0f;
    for (int h = 0; h < Hc; h += 4) {
        float4 w = *(const float4*)(wr + h);
#pragma unroll
        for (int ss = 0; ss < 8; ++ss) {
            acc[ss] = fmaf(w.x, se[ss][h + 0], acc[ss]);
            acc[ss] = fmaf(w.y, se[ss][h + 1], acc[ss]);
            acc[ss] = fmaf(w.z, se[ss][h + 2], acc[ss]);
            acc[ss] = fmaf(w.w, se[ss][h + 3], acc[ss]);
        }
    }
#pragma unroll
    for (int ss = 0; ss < 8; ++ss)
        proj[((size_t)b * Sc + s0 + ss) * Hc + k] = acc[ss];
}

// Persistent decode loop. h_all/ah_all rotate per step (write-once addresses);
// c is in-place (only ever touched by the same thread). All arithmetic chains
// are bit-identical to the verified round-0 multi-launch kernels.
__global__ __launch_bounds__(256) void k_loop(
    const int* __restrict__ tgt, const int* __restrict__ len_src,
    const float* __restrict__ enc, const float* __restrict__ h0,
    const float* __restrict__ c0, const float* __restrict__ emb,
    const float* __restrict__ W_ih, const float* __restrict__ W_hh,
    const float* __restrict__ b_ih, const float* __restrict__ b_hh,
    const float* __restrict__ proj, const float* __restrict__ W_c,
    const float* __restrict__ b_c,
    float* __restrict__ h_all, float* __restrict__ cbuf,
    float* __restrict__ ah_all, unsigned int* __restrict__ cnt) {
    int blk = blockIdx.x, tid = threadIdx.x;
    unsigned int gen = 0;

    // prologue == k_init (write-through: read cross-XCD after the barrier)
    {
        int i = blk * 256 + tid;
        if (i < BH) {
            stg(&h_all[i], h0[i]);
            stg(&cbuf[i], c0[i]);
            stg(&ah_all[i], 0.0f);
        }
    }
    gbar(cnt, ++gen * NBLK);

    __shared__ float sg[2][4][32];
    __shared__ __align__(16) float sh[Hc];    // h2 for this batch
    __shared__ __align__(16) float scv[Hc];   // ctx for this batch
    __shared__ float ss[Sc];
    __shared__ float sal[Sc];

    for (int t = 0; t < Tc - 1; ++t) {
        const float* hP = h_all + (size_t)t * BH;
        float*       hN = h_all + (size_t)(t + 1) * BH;
        const float* aP = ah_all + (size_t)t * BH;
        float*       aN = ah_all + (size_t)(t + 1) * BH;

        // ---------------- phase 1: k_step1 (all 256 blocks) ----------------
        {
            int b  = tid & 31;
            int q  = (tid >> 5) & 3;
            int hl = tid >> 7;
            int h  = blk * 2 + hl;
            int j  = q * Hc + h;
            int w  = tgt[b * Tc + t];
            const float* x  = emb + (size_t)w * Ec;
            const float* wi = W_ih + (size_t)j * (Ec + Hc);
            const float* wh = W_hh + (size_t)j * Hc;
            const float* ap = aP + b * Hc;
            const float* hp = hP + b * Hc;
            float a0 = 0.f, a1 = 0.f, a2 = 0.f, a3 = 0.f;
            for (int e = 0; e < Ec; e += 16) {
                a0 += dot4(x + e, wi + e);
                a1 += dot4(x + e + 4, wi + e + 4);
                a2 += dot4(x + e + 8, wi + e + 8);
                a3 += dot4(x + e + 12, wi + e + 12);
            }
            for (int k = 0; k < Hc; k += 16) {
                a0 += dot4(ap + k, wi + Ec + k);
                a1 += dot4(ap + k + 4, wi + Ec + k + 4);
                a2 += dot4(ap + k + 8, wi + Ec + k + 8);
                a3 += dot4(ap + k + 12, wi + Ec + k + 12);
            }
            for (int k = 0; k < Hc; k += 16) {
                a0 += dot4(hp + k, wh + k);
                a1 += dot4(hp + k + 4, wh + k + 4);
                a2 += dot4(hp + k + 8, wh + k + 8);
                a3 += dot4(hp + k + 12, wh + k + 12);
            }
            float acc = b_ih[j] + b_hh[j] + ((a0 + a1) + (a2 + a3));
            sg[hl][q][b] = acc;
            __syncthreads();
            if (q == 0) {
                float iv = sigf(sg[hl][0][b]);
                float fv = sigf(sg[hl][1][b]);
                float gv = tanhf(sg[hl][2][b]);
                float ov = sigf(sg[hl][3][b]);
                int idx = b * Hc + h;
                float c2 = fv * cbuf[idx] + iv * gv;
                float h2v = ov * tanhf(c2);
                cbuf[idx] = c2;        // same-thread read/write only: cacheable
                stg(&hN[idx], h2v);    // crosses barrier: write-through
            }
        }
        gbar(cnt, ++gen * NBLK);

        // ------- phase 2/3/4: k_score + k_ctx + k_wc (blocks 0..31) -------
        if (blk < Bc) {
            int b = blk;
            for (int k = tid; k < Hc; k += 256) sh[k] = hN[b * Hc + k];
            __syncthreads();
            // scores (k_score chain)
            {
                int s = tid >> 2, r = tid & 3;
                const float* pr = proj + ((size_t)b * Sc + s) * Hc + r * 128;
                const float* hh = sh + r * 128;
                float p0 = 0.f, p1 = 0.f;
                for (int k = 0; k < 128; k += 8) {
                    p0 += dot4(hh + k, pr + k);
                    p1 += dot4(hh + k + 4, pr + k + 4);
                }
                float p = p0 + p1;
                p += __shfl_xor(p, 1);
                p += __shfl_xor(p, 2);
                if (r == 0) ss[s] = p;
            }
            __syncthreads();
            // masked softmax (k_score chain), lanes 0..63 of wave 0
            if (tid < Sc) {
                int len = len_src[b];
                float sc = (tid < len) ? ss[tid] : NEGC;
                float mx = sc;
#pragma unroll
                for (int m = 32; m >= 1; m >>= 1) mx = fmaxf(mx, __shfl_xor(mx, m));
                float p = expf(sc - mx);
                float sum = p;
#pragma unroll
                for (int m = 32; m >= 1; m >>= 1) sum += __shfl_xor(sum, m);
                sal[tid] = p / sum;
            }
            __syncthreads();
            // ctx (k_ctx chain): per h, two 32-long serial chains + one add
#pragma unroll
            for (int rep = 0; rep < 2; ++rep) {
                int h = tid + rep * 256;
                float accA = 0.0f, accB = 0.0f;
                for (int s = 0; s < 32; ++s)
                    accA = fmaf(sal[s], enc[((size_t)s * Bc + b) * Hc + h], accA);
                for (int s = 32; s < 64; ++s)
                    accB = fmaf(sal[s], enc[((size_t)s * Bc + b) * Hc + h], accB);
                scv[h] = accA + accB;
            }
            __syncthreads();
            // Wc (k_wc chain): each thread does k = tid and k = tid+256
#pragma unroll
            for (int rep = 0; rep < 2; ++rep) {
                int k = tid + rep * 256;
                const float* wc = W_c + (size_t)k * (2 * Hc);
                float a0 = 0.f, a1 = 0.f, a2 = 0.f, a3 = 0.f;
                for (int j = 0; j < Hc; j += 16) {
                    a0 += dot4(sh + j, wc + j);
                    a1 += dot4(sh + j + 4, wc + j + 4);
                    a2 += dot4(sh + j + 8, wc + j + 8);
                    a3 += dot4(sh + j + 12, wc + j + 12);
                }
                const float* wc2 = wc + Hc;
                for (int j = 0; j < Hc; j += 16) {
                    a0 += dot4(scv + j, wc2 + j);
                    a1 += dot4(scv + j + 4, wc2 + j + 4);
                    a2 += dot4(scv + j + 8, wc2 + j + 8);
                    a3 += dot4(scv + j + 12, wc2 + j + 12);
                }
                stg(&aN[b * Hc + k], tanhf(b_c[k] + ((a0 + a1) + (a2 + a3))));
            }
        }
        gbar(cnt, ++gen * NBLK);
    }
}

// Batched logits GEMM: C[m][n] = A[m][:] . W_o[n][:] + b_o[n]
__global__ __launch_bounds__(256) void k_biglogits(const float* __restrict__ A,
                                                   const float* __restrict__ W_o,
                                                   const float* __restrict__ b_o,
                                                   float* __restrict__ out) {
    __shared__ float At[32][128];
    __shared__ float Bt[32][128];
    int tid = threadIdx.x;
    int n_base = blockIdx.x * 128;
    int m_base = blockIdx.y * 128;
    int tn = tid & 15, tm = tid >> 4;

    float acc[2][4][2][4];
#pragma unroll
    for (int mg = 0; mg < 2; ++mg)
#pragma unroll
        for (int mi = 0; mi < 4; ++mi)
#pragma unroll
            for (int ng = 0; ng < 2; ++ng)
#pragma unroll
                for (int ni = 0; ni < 4; ++ni) acc[mg][mi][ng][ni] = 0.0f;

    int srow = tid >> 1;
    int koff = (tid & 1) * 16;
    int gm = m_base + srow;
    const float* arow = A + (size_t)gm * Hc + koff;
    const float* brow = W_o + (size_t)(n_base + srow) * Hc + koff;

    for (int kc = 0; kc < Hc; kc += 32) {
        float av[16], bv[16];
#pragma unroll
        for (int i = 0; i < 4; ++i) {
            float4 t4 = (gm < Mtot) ? *(const float4*)(arow + kc + i * 4)
                                    : make_float4(0.f, 0.f, 0.f, 0.f);
            av[i * 4 + 0] = t4.x; av[i * 4 + 1] = t4.y; av[i * 4 + 2] = t4.z; av[i * 4 + 3] = t4.w;
            float4 u4 = *(const float4*)(brow + kc + i * 4);
            bv[i * 4 + 0] = u4.x; bv[i * 4 + 1] = u4.y; bv[i * 4 + 2] = u4.z; bv[i * 4 + 3] = u4.w;
        }
        __syncthreads();
#pragma unroll
        for (int i = 0; i < 16; ++i) {
            At[koff + i][srow] = av[i];
            Bt[koff + i][srow] = bv[i];
        }
        __syncthreads();
#pragma unroll
        for (int k = 0; k < 32; ++k) {
            float4 a0 = *(const float4*)&At[k][tm * 4];
            float4 a1 = *(const float4*)&At[k][64 + tm * 4];
            float4 b0 = *(const float4*)&Bt[k][tn * 4];
            float4 b1 = *(const float4*)&Bt[k][64 + tn * 4];
            float am[2][4] = {{a0.x, a0.y, a0.z, a0.w}, {a1.x, a1.y, a1.z, a1.w}};
            float bn[2][4] = {{b0.x, b0.y, b0.z, b0.w}, {b1.x, b1.y, b1.z, b1.w}};
#pragma unroll
            for (int mg = 0; mg < 2; ++mg)
#pragma unroll
                for (int mi = 0; mi < 4; ++mi)
#pragma unroll
                    for (int ng = 0; ng < 2; ++ng)
#pragma unroll
                        for (int ni = 0; ni < 4; ++ni)
                            acc[mg][mi][ng][ni] = fmaf(am[mg][mi], bn[ng][ni], acc[mg][mi][ng][ni]);
        }
        __syncthreads();
    }

#pragma unroll
    for (int ng = 0; ng < 2; ++ng) {
        int n = n_base + ng * 64 + tn * 4;
        float4 bo = *(const float4*)(b_o + n);
#pragma unroll
        for (int mg = 0; mg < 2; ++mg)
#pragma unroll
            for (int mi = 0; mi < 4; ++mi) {
                int m = m_base + mg * 64 + tm * 4 + mi;
                if (m < Mtot) {
                    float4 v;
                    v.x = acc[mg][mi][ng][0] + bo.x;
                    v.y = acc[mg][mi][ng][1] + bo.y;
                    v.z = acc[mg][mi][ng][2] + bo.z;
                    v.w = acc[mg][mi][ng][3] + bo.w;
                    *(float4*)(out + (size_t)m * Vc + n) = v;
                }
            }
    }
}

// Per row m: argmax (first tiebreak) + logsumexp, then subtract in place; words out.
__global__ __launch_bounds__(256) void k_reduce_norm(float* __restrict__ out,
                                                     float* __restrict__ words) {
    int m = blockIdx.x, tid = threadIdx.x;
    float* row = out + (size_t)m * Vc;
    float mx = -INFINITY;
    int mi = 0;
    for (int v = tid; v < Vc; v += 256) {
        float x = row[v];
        if (x > mx) { mx = x; mi = v; }
    }
    __shared__ float smx[256];
    __shared__ int smi[256];
    __shared__ float ssum[256];
    smx[tid] = mx; smi[tid] = mi;
    __syncthreads();
    for (int off = 128; off; off >>= 1) {
        if (tid < off) {
            float o = smx[tid + off]; int oi = smi[tid + off];
            if (o > smx[tid] || (o == smx[tid] && oi < smi[tid])) { smx[tid] = o; smi[tid] = oi; }
        }
        __syncthreads();
    }
    float gmx = smx[0];
    float s = 0.0f;
    for (int v = tid; v < Vc; v += 256) s += expf(row[v] - gmx);
    ssum[tid] = s;
    __syncthreads();
    for (int off = 128; off; off >>= 1) {
        if (tid < off) ssum[tid] += ssum[tid + off];
        __syncthreads();
    }
    float lse = gmx + logf(ssum[0]);
    __syncthreads();
    for (int v = tid; v < Vc; v += 256) row[v] -= lse;
    if (tid == 0) words[m] = (float)smi[0];
}

extern "C" void kernel_launch(void* const* d_in, const int* in_sizes, int n_in,
                              void* d_out, int out_size, void* d_ws, size_t ws_size,
                              hipStream_t stream) {
    const int*   tgt     = (const int*)d_in[0];
    const int*   len_src = (const int*)d_in[1];
    const float* enc     = (const float*)d_in[2];
    const float* h0      = (const float*)d_in[3];
    const float* c0      = (const float*)d_in[4];
    const float* emb     = (const float*)d_in[5];
    const float* W_ih    = (const float*)d_in[6];
    const float* W_hh    = (const float*)d_in[7];
    const float* b_ih    = (const float*)d_in[8];
    const float* b_hh    = (const float*)d_in[9];
    const float* W_a     = (const float*)d_in[10];
    const float* W_c     = (const float*)d_in[11];
    const float* b_c     = (const float*)d_in[12];
    const float* W_o     = (const float*)d_in[13];
    const float* b_o     = (const float*)d_in[14];

    float* out = (float*)d_out;
    float* ws = (float*)d_ws;

    float* proj   = ws;                            // B*S*H = 1,048,576
    float* h_all  = proj + (size_t)Bc * Sc * Hc;   // 32 * BH (write-once slots)
    float* cbuf   = h_all + 32 * (size_t)BH;       // BH (in-place)
    float* ah_all = cbuf + BH;                     // 32 * BH (slot0 = zeros)
    unsigned int* cnt = (unsigned int*)(ah_all + 32 * (size_t)BH);
    float* out_words = out + (size_t)(Tc - 1) * Bc * Vc;

    {
        dim3 g(Hc / 256, Sc / 8, Bc);
        k_proj<<<g, 256, 0, stream>>>(W_a, enc, proj, cnt);
    }

    k_loop<<<NBLK, 256, 0, stream>>>(tgt, len_src, enc, h0, c0, emb,
                                     W_ih, W_hh, b_ih, b_hh, proj, W_c, b_c,
                                     h_all, cbuf, ah_all, cnt);

    {
        dim3 g(Vc / 128, (Mtot + 127) / 128);    // 250 x 8
        k_biglogits<<<g, 256, 0, stream>>>(ah_all + BH, W_o, b_o, out);
    }
    k_reduce_norm<<<Mtot, 256, 0, stream>>>(out, out_words);
}

// Round 5
// 3427.983 us; speedup vs baseline: 1.8270x; 1.5872x over previous
//
#include <hip/hip_runtime.h>
#include <cmath>

#define Bc 32
#define Tc 32
#define Sc 64
#define Hc 512
#define Ec 512
#define Vc 32000
#define NEGC (-1e9f)
#define BH (Bc * Hc)
#define Mtot ((Tc - 1) * Bc)   // 992
#define NBLK 256
#define SLOT_PAD 16            // one 64B line per arrival slot

__device__ __forceinline__ float sigf(float x) { return 1.0f / (1.0f + expf(-x)); }

__device__ __forceinline__ float dot4(const float* a, const float* b) {
    float4 x = *(const float4*)a;
    float4 y = *(const float4*)b;
    return x.x * y.x + x.y * y.y + x.z * y.z + x.w * y.w;
}

// Write-through store to the device coherence point. Used for all data that
// crosses a grid barrier; those buffers rotate per step (write-once addresses)
// so cached reads can never see stale lines -> barrier needs no cache maint.
__device__ __forceinline__ void stg(float* p, float v) {
    __hip_atomic_store(p, v, __ATOMIC_RELAXED, __HIP_MEMORY_SCOPE_AGENT);
}

// Contention-free grid barrier:
//  - arrival: each block writes its OWN padded slot (parallel, no RMW chain)
//  - detection: block 0's 256 threads poll one slot each (loads pipelined)
//  - release: single 'go' word; 255 blocks poll read-only (no ownership bounce)
// No cache-maintenance instructions (see stg comment). vmcnt(0) drains this
// wave's through-stores to the coherence point before signaling arrival.
__device__ __forceinline__ void gbar(unsigned int* slots, unsigned int* go,
                                     unsigned int gen) {
    asm volatile("s_waitcnt vmcnt(0)" ::: "memory");
    __syncthreads();
    if (blockIdx.x == 0) {
        int i = threadIdx.x;
        if (i > 0)
            while (__hip_atomic_load(&slots[i * SLOT_PAD], __ATOMIC_RELAXED,
                                     __HIP_MEMORY_SCOPE_AGENT) < gen)
                __builtin_amdgcn_s_sleep(1);
        __syncthreads();
        if (threadIdx.x == 0)
            __hip_atomic_store(go, gen, __ATOMIC_RELAXED, __HIP_MEMORY_SCOPE_AGENT);
    } else {
        if (threadIdx.x == 0) {
            __hip_atomic_store(&slots[blockIdx.x * SLOT_PAD], gen,
                               __ATOMIC_RELAXED, __HIP_MEMORY_SCOPE_AGENT);
            while (__hip_atomic_load(go, __ATOMIC_RELAXED,
                                     __HIP_MEMORY_SCOPE_AGENT) < gen)
                __builtin_amdgcn_s_sleep(1);
        }
        __syncthreads();
    }
    asm volatile("" ::: "memory");
}

// proj[b][s][k] = sum_h W_a[k][h] * enc[s][b][h]   (+ resets barrier state)
__global__ __launch_bounds__(256) void k_proj(const float* __restrict__ W_a,
                                              const float* __restrict__ enc,
                                              float* __restrict__ proj,
                                              unsigned int* __restrict__ bar) {
    if (blockIdx.x == 0 && blockIdx.y == 0 && blockIdx.z == 0) {
        bar[threadIdx.x * SLOT_PAD] = 0u;             // arrival slots
        if (threadIdx.x == 0) bar[NBLK * SLOT_PAD] = 0u;  // go word
    }
    int k = blockIdx.x * 256 + threadIdx.x;
    int s0 = blockIdx.y * 8;
    int b = blockIdx.z;
    __shared__ float se[8][Hc];
    for (int i = threadIdx.x; i < 8 * Hc; i += 256) {
        int ss = i >> 9, hh = i & (Hc - 1);
        se[ss][hh] = enc[((size_t)(s0 + ss) * Bc + b) * Hc + hh];
    }
    __syncthreads();
    const float* wr = W_a + (size_t)k * Hc;
    float acc[8];
#pragma unroll
    for (int ss = 0; ss < 8; ++ss) acc[ss] = 0.0f;
    for (int h = 0; h < Hc; h += 4) {
        float4 w = *(const float4*)(wr + h);
#pragma unroll
        for (int ss = 0; ss < 8; ++ss) {
            acc[ss] = fmaf(w.x, se[ss][h + 0], acc[ss]);
            acc[ss] = fmaf(w.y, se[ss][h + 1], acc[ss]);
            acc[ss] = fmaf(w.z, se[ss][h + 2], acc[ss]);
            acc[ss] = fmaf(w.w, se[ss][h + 3], acc[ss]);
        }
    }
#pragma unroll
    for (int ss = 0; ss < 8; ++ss)
        proj[((size_t)b * Sc + s0 + ss) * Hc + k] = acc[ss];
}

// Persistent decode loop, 3 barriers/step:
//  phase 1 (all 256 blocks): gates GEMM + LSTM        == k_step1 chains
//  phase 2/3 (blocks 0..31): score+softmax+ctx->ctxN  == k_score/k_ctx chains
//  phase 4 (all 256 blocks): Wc GEMV, 2 fixed W_c rows/block, 4 lanes/output
//                            (a0..a3 sub-chains + xor-shuffle == k_wc chain)
// Each block re-reads the SAME weight rows every step -> per-XCD working set
// ~3MB < 4MB L2 -> weights fetched from HBM once, not 31x.
__global__ __launch_bounds__(256) void k_loop(
    const int* __restrict__ tgt, const int* __restrict__ len_src,
    const float* __restrict__ enc, const float* __restrict__ h0,
    const float* __restrict__ c0, const float* __restrict__ emb,
    const float* __restrict__ W_ih, const float* __restrict__ W_hh,
    const float* __restrict__ b_ih, const float* __restrict__ b_hh,
    const float* __restrict__ proj, const float* __restrict__ W_c,
    const float* __restrict__ b_c,
    float* __restrict__ h_all, float* __restrict__ cbuf,
    float* __restrict__ ah_all, float* __restrict__ ctx_all,
    unsigned int* __restrict__ bar) {
    int blk = blockIdx.x, tid = threadIdx.x;
    unsigned int* slots = bar;
    unsigned int* go = bar + NBLK * SLOT_PAD;
    unsigned int gen = 0;

    // prologue == k_init (write-through: read cross-XCD after the barrier)
    {
        int i = blk * 256 + tid;
        if (i < BH) {
            stg(&h_all[i], h0[i]);
            stg(&cbuf[i], c0[i]);
            stg(&ah_all[i], 0.0f);
        }
    }
    gbar(slots, go, ++gen);

    __shared__ float sg[2][4][32];
    __shared__ __align__(16) float sh[Hc];    // h2 for this batch (blocks<32)
    __shared__ float ss[Sc];
    __shared__ float sal[Sc];

    for (int t = 0; t < Tc - 1; ++t) {
        const float* hP = h_all + (size_t)t * BH;
        float*       hN = h_all + (size_t)(t + 1) * BH;
        const float* aP = ah_all + (size_t)t * BH;
        float*       aN = ah_all + (size_t)(t + 1) * BH;
        float*       ctxN = ctx_all + (size_t)t * BH;

        // ---------------- phase 1: k_step1 (all 256 blocks) ----------------
        {
            int b  = tid & 31;
            int q  = (tid >> 5) & 3;
            int hl = tid >> 7;
            int h  = blk * 2 + hl;
            int j  = q * Hc + h;
            int w  = tgt[b * Tc + t];
            const float* x  = emb + (size_t)w * Ec;
            const float* wi = W_ih + (size_t)j * (Ec + Hc);
            const float* wh = W_hh + (size_t)j * Hc;
            const float* ap = aP + b * Hc;
            const float* hp = hP + b * Hc;
            float a0 = 0.f, a1 = 0.f, a2 = 0.f, a3 = 0.f;
            for (int e = 0; e < Ec; e += 16) {
                a0 += dot4(x + e, wi + e);
                a1 += dot4(x + e + 4, wi + e + 4);
                a2 += dot4(x + e + 8, wi + e + 8);
                a3 += dot4(x + e + 12, wi + e + 12);
            }
            for (int k = 0; k < Hc; k += 16) {
                a0 += dot4(ap + k, wi + Ec + k);
                a1 += dot4(ap + k + 4, wi + Ec + k + 4);
                a2 += dot4(ap + k + 8, wi + Ec + k + 8);
                a3 += dot4(ap + k + 12, wi + Ec + k + 12);
            }
            for (int k = 0; k < Hc; k += 16) {
                a0 += dot4(hp + k, wh + k);
                a1 += dot4(hp + k + 4, wh + k + 4);
                a2 += dot4(hp + k + 8, wh + k + 8);
                a3 += dot4(hp + k + 12, wh + k + 12);
            }
            float acc = b_ih[j] + b_hh[j] + ((a0 + a1) + (a2 + a3));
            sg[hl][q][b] = acc;
            __syncthreads();
            if (q == 0) {
                float iv = sigf(sg[hl][0][b]);
                float fv = sigf(sg[hl][1][b]);
                float gv = tanhf(sg[hl][2][b]);
                float ov = sigf(sg[hl][3][b]);
                int idx = b * Hc + h;
                float c2 = fv * cbuf[idx] + iv * gv;
                float h2v = ov * tanhf(c2);
                cbuf[idx] = c2;        // same-thread read/write only: cacheable
                stg(&hN[idx], h2v);    // crosses barrier: write-through
            }
        }
        gbar(slots, go, ++gen);

        // --------- phase 2/3: k_score + k_ctx (blocks 0..31, b=blk) ---------
        if (blk < Bc) {
            int b = blk;
            for (int k = tid; k < Hc; k += 256) sh[k] = hN[b * Hc + k];
            __syncthreads();
            // scores (k_score chain)
            {
                int s = tid >> 2, r = tid & 3;
                const float* pr = proj + ((size_t)b * Sc + s) * Hc + r * 128;
                const float* hh = sh + r * 128;
                float p0 = 0.f, p1 = 0.f;
                for (int k = 0; k < 128; k += 8) {
                    p0 += dot4(hh + k, pr + k);
                    p1 += dot4(hh + k + 4, pr + k + 4);
                }
                float p = p0 + p1;
                p += __shfl_xor(p, 1);
                p += __shfl_xor(p, 2);
                if (r == 0) ss[s] = p;
            }
            __syncthreads();
            // masked softmax (k_score chain), lanes 0..63 of wave 0
            if (tid < Sc) {
                int len = len_src[b];
                float sc = (tid < len) ? ss[tid] : NEGC;
                float mx = sc;
#pragma unroll
                for (int m = 32; m >= 1; m >>= 1) mx = fmaxf(mx, __shfl_xor(mx, m));
                float p = expf(sc - mx);
                float sum = p;
#pragma unroll
                for (int m = 32; m >= 1; m >>= 1) sum += __shfl_xor(sum, m);
                sal[tid] = p / sum;
            }
            __syncthreads();
            // ctx (k_ctx chain): per h, two 32-long serial chains + one add
#pragma unroll
            for (int rep = 0; rep < 2; ++rep) {
                int h = tid + rep * 256;
                float accA = 0.0f, accB = 0.0f;
                for (int s = 0; s < 32; ++s)
                    accA = fmaf(sal[s], enc[((size_t)s * Bc + b) * Hc + h], accA);
                for (int s = 32; s < 64; ++s)
                    accB = fmaf(sal[s], enc[((size_t)s * Bc + b) * Hc + h], accB);
                stg(&ctxN[b * Hc + h], accA + accB);
            }
        }
        gbar(slots, go, ++gen);

        // ------------- phase 4: Wc GEMV (all 256 blocks) -------------
        // block owns W_c rows {2*blk, 2*blk+1} (same rows every step -> L2-hit).
        // 4 lanes per output compute the k_wc a0..a3 sub-chains; combine
        // ((a0+a1)+(a2+a3)) via xor-shuffles (fp add is bitwise commutative).
        {
            int r   = tid & 3;          // sub-chain index 0..3
            int out = tid >> 2;         // 0..63
            int b   = out >> 1;
            int kl  = out & 1;
            int k   = blk * 2 + kl;
            const float* wc  = W_c + (size_t)k * (2 * Hc) + 4 * r;
            const float* wc2 = wc + Hc;
            const float* hp  = hN + b * Hc + 4 * r;
            const float* cp  = ctxN + b * Hc + 4 * r;
            float ar = 0.f;
            for (int j = 0; j < Hc; j += 16)
                ar += dot4(hp + j, wc + j);
            for (int j = 0; j < Hc; j += 16)
                ar += dot4(cp + j, wc2 + j);
            float v01 = ar + __shfl_xor(ar, 1);   // (a0+a1) on lanes 0/1 pairs
            float v   = v01 + __shfl_xor(v01, 2); // ((a0+a1)+(a2+a3))
            if (r == 0)
                stg(&aN[b * Hc + k], tanhf(b_c[k] + v));
        }
        gbar(slots, go, ++gen);
    }
}

// Batched logits GEMM: C[m][n] = A[m][:] . W_o[n][:] + b_o[n]
__global__ __launch_bounds__(256) void k_biglogits(const float* __restrict__ A,
                                                   const float* __restrict__ W_o,
                                                   const float* __restrict__ b_o,
                                                   float* __restrict__ out) {
    __shared__ float At[32][128];
    __shared__ float Bt[32][128];
    int tid = threadIdx.x;
    int n_base = blockIdx.x * 128;
    int m_base = blockIdx.y * 128;
    int tn = tid & 15, tm = tid >> 4;

    float acc[2][4][2][4];
#pragma unroll
    for (int mg = 0; mg < 2; ++mg)
#pragma unroll
        for (int mi = 0; mi < 4; ++mi)
#pragma unroll
            for (int ng = 0; ng < 2; ++ng)
#pragma unroll
                for (int ni = 0; ni < 4; ++ni) acc[mg][mi][ng][ni] = 0.0f;

    int srow = tid >> 1;
    int koff = (tid & 1) * 16;
    int gm = m_base + srow;
    const float* arow = A + (size_t)gm * Hc + koff;
    const float* brow = W_o + (size_t)(n_base + srow) * Hc + koff;

    for (int kc = 0; kc < Hc; kc += 32) {
        float av[16], bv[16];
#pragma unroll
        for (int i = 0; i < 4; ++i) {
            float4 t4 = (gm < Mtot) ? *(const float4*)(arow + kc + i * 4)
                                    : make_float4(0.f, 0.f, 0.f, 0.f);
            av[i * 4 + 0] = t4.x; av[i * 4 + 1] = t4.y; av[i * 4 + 2] = t4.z; av[i * 4 + 3] = t4.w;
            float4 u4 = *(const float4*)(brow + kc + i * 4);
            bv[i * 4 + 0] = u4.x; bv[i * 4 + 1] = u4.y; bv[i * 4 + 2] = u4.z; bv[i * 4 + 3] = u4.w;
        }
        __syncthreads();
#pragma unroll
        for (int i = 0; i < 16; ++i) {
            At[koff + i][srow] = av[i];
            Bt[koff + i][srow] = bv[i];
        }
        __syncthreads();
#pragma unroll
        for (int k = 0; k < 32; ++k) {
            float4 a0 = *(const float4*)&At[k][tm * 4];
            float4 a1 = *(const float4*)&At[k][64 + tm * 4];
            float4 b0 = *(const float4*)&Bt[k][tn * 4];
            float4 b1 = *(const float4*)&Bt[k][64 + tn * 4];
            float am[2][4] = {{a0.x, a0.y, a0.z, a0.w}, {a1.x, a1.y, a1.z, a1.w}};
            float bn[2][4] = {{b0.x, b0.y, b0.z, b0.w}, {b1.x, b1.y, b1.z, b1.w}};
#pragma unroll
            for (int mg = 0; mg < 2; ++mg)
#pragma unroll
                for (int mi = 0; mi < 4; ++mi)
#pragma unroll
                    for (int ng = 0; ng < 2; ++ng)
#pragma unroll
                        for (int ni = 0; ni < 4; ++ni)
                            acc[mg][mi][ng][ni] = fmaf(am[mg][mi], bn[ng][ni], acc[mg][mi][ng][ni]);
        }
        __syncthreads();
    }

#pragma unroll
    for (int ng = 0; ng < 2; ++ng) {
        int n = n_base + ng * 64 + tn * 4;
        float4 bo = *(const float4*)(b_o + n);
#pragma unroll
        for (int mg = 0; mg < 2; ++mg)
#pragma unroll
            for (int mi = 0; mi < 4; ++mi) {
                int m = m_base + mg * 64 + tm * 4 + mi;
                if (m < Mtot) {
                    float4 v;
                    v.x = acc[mg][mi][ng][0] + bo.x;
                    v.y = acc[mg][mi][ng][1] + bo.y;
                    v.z = acc[mg][mi][ng][2] + bo.z;
                    v.w = acc[mg][mi][ng][3] + bo.w;
                    *(float4*)(out + (size_t)m * Vc + n) = v;
                }
            }
    }
}

// Per row m: argmax (first tiebreak) + logsumexp, then subtract in place; words out.
__global__ __launch_bounds__(256) void k_reduce_norm(float* __restrict__ out,
                                                     float* __restrict__ words) {
    int m = blockIdx.x, tid = threadIdx.x;
    float* row = out + (size_t)m * Vc;
    float mx = -INFINITY;
    int mi = 0;
    for (int v = tid; v < Vc; v += 256) {
        float x = row[v];
        if (x > mx) { mx = x; mi = v; }
    }
    __shared__ float smx[256];
    __shared__ int smi[256];
    __shared__ float ssum[256];
    smx[tid] = mx; smi[tid] = mi;
    __syncthreads();
    for (int off = 128; off; off >>= 1) {
        if (tid < off) {
            float o = smx[tid + off]; int oi = smi[tid + off];
            if (o > smx[tid] || (o == smx[tid] && oi < smi[tid])) { smx[tid] = o; smi[tid] = oi; }
        }
        __syncthreads();
    }
    float gmx = smx[0];
    float s = 0.0f;
    for (int v = tid; v < Vc; v += 256) s += expf(row[v] - gmx);
    ssum[tid] = s;
    __syncthreads();
    for (int off = 128; off; off >>= 1) {
        if (tid < off) ssum[tid] += ssum[tid + off];
        __syncthreads();
    }
    float lse = gmx + logf(ssum[0]);
    __syncthreads();
    for (int v = tid; v < Vc; v += 256) row[v] -= lse;
    if (tid == 0) words[m] = (float)smi[0];
}

extern "C" void kernel_launch(void* const* d_in, const int* in_sizes, int n_in,
                              void* d_out, int out_size, void* d_ws, size_t ws_size,
                              hipStream_t stream) {
    const int*   tgt     = (const int*)d_in[0];
    const int*   len_src = (const int*)d_in[1];
    const float* enc     = (const float*)d_in[2];
    const float* h0      = (const float*)d_in[3];
    const float* c0      = (const float*)d_in[4];
    const float* emb     = (const float*)d_in[5];
    const float* W_ih    = (const float*)d_in[6];
    const float* W_hh    = (const float*)d_in[7];
    const float* b_ih    = (const float*)d_in[8];
    const float* b_hh    = (const float*)d_in[9];
    const float* W_a     = (const float*)d_in[10];
    const float* W_c     = (const float*)d_in[11];
    const float* b_c     = (const float*)d_in[12];
    const float* W_o     = (const float*)d_in[13];
    const float* b_o     = (const float*)d_in[14];

    float* out = (float*)d_out;
    float* ws = (float*)d_ws;

    float* proj    = ws;                             // B*S*H = 1,048,576
    float* h_all   = proj + (size_t)Bc * Sc * Hc;    // 32 * BH (write-once slots)
    float* cbuf    = h_all + 32 * (size_t)BH;        // BH (same-thread in-place)
    float* ah_all  = cbuf + BH;                      // 32 * BH (slot0 = zeros)
    float* ctx_all = ah_all + 32 * (size_t)BH;       // 31 * BH (write-once slots)
    unsigned int* bar = (unsigned int*)(ctx_all + 31 * (size_t)BH);
    float* out_words = out + (size_t)(Tc - 1) * Bc * Vc;

    {
        dim3 g(Hc / 256, Sc / 8, Bc);
        k_proj<<<g, 256, 0, stream>>>(W_a, enc, proj, bar);
    }

    k_loop<<<NBLK, 256, 0, stream>>>(tgt, len_src, enc, h0, c0, emb,
                                     W_ih, W_hh, b_ih, b_hh, proj, W_c, b_c,
                                     h_all, cbuf, ah_all, ctx_all, bar);

    {
        dim3 g(Vc / 128, (Mtot + 127) / 128);    // 250 x 8
        k_biglogits<<<g, 256, 0, stream>>>(ah_all + BH, W_o, b_o, out);
    }
    k_reduce_norm<<<Mtot, 256, 0, stream>>>(out, out_words);
}

// Round 6
// 3389.761 us; speedup vs baseline: 1.8476x; 1.0113x over previous
//
#include <hip/hip_runtime.h>
#include <cmath>

#define Bc 32
#define Tc 32
#define Sc 64
#define Hc 512
#define Ec 512
#define Vc 32000
#define NEGC (-1e9f)
#define BH (Bc * Hc)
#define Mtot ((Tc - 1) * Bc)   // 992
#define NBLK 256
#define SLOT_PAD 32            // one 128B line per arrival slot
#define GO_LINES 32            // release broadcast lines
#define GO_GROUP (NBLK / GO_LINES)   // 8 blocks poll each go line

__device__ __forceinline__ float sigf(float x) { return 1.0f / (1.0f + expf(-x)); }

__device__ __forceinline__ float dot4(const float* a, const float* b) {
    float4 x = *(const float4*)a;
    float4 y = *(const float4*)b;
    return x.x * y.x + x.y * y.y + x.z * y.z + x.w * y.w;
}

// Write-through store to the device coherence point. Used for all data that
// crosses a grid barrier; those buffers rotate per step (write-once addresses)
// so cached reads can never see stale lines -> barrier needs no cache maint.
__device__ __forceinline__ void stg(float* p, float v) {
    __hip_atomic_store(p, v, __ATOMIC_RELAXED, __HIP_MEMORY_SCOPE_AGENT);
}

// Contention-free grid barrier, v2:
//  - arrival: each block writes its OWN 128B-padded slot (parallel stores)
//  - detection: block 0's 256 threads poll one slot each (distinct lines)
//  - release: 32 'go' lines; block blk polls go[blk/8] -> <=8 pollers/line.
//    (round-5's single go line had 255 agent-scope pollers serializing at one
//     line port ~= 20us/poll-round; that WAS the barrier cost.)
// No cache-maintenance instructions (see stg comment). vmcnt(0) drains this
// wave's through-stores to the coherence point before signaling arrival.
__device__ __forceinline__ void gbar(unsigned int* slots, unsigned int* go,
                                     unsigned int gen) {
    asm volatile("s_waitcnt vmcnt(0)" ::: "memory");
    __syncthreads();
    if (blockIdx.x == 0) {
        int i = threadIdx.x;
        if (i > 0)
            while (__hip_atomic_load(&slots[i * SLOT_PAD], __ATOMIC_RELAXED,
                                     __HIP_MEMORY_SCOPE_AGENT) < gen)
                __builtin_amdgcn_s_sleep(1);
        __syncthreads();
        if (threadIdx.x < GO_LINES)
            __hip_atomic_store(&go[threadIdx.x * SLOT_PAD], gen,
                               __ATOMIC_RELAXED, __HIP_MEMORY_SCOPE_AGENT);
    } else {
        if (threadIdx.x == 0) {
            __hip_atomic_store(&slots[blockIdx.x * SLOT_PAD], gen,
                               __ATOMIC_RELAXED, __HIP_MEMORY_SCOPE_AGENT);
            unsigned int* myline = &go[(blockIdx.x / GO_GROUP) * SLOT_PAD];
            while (__hip_atomic_load(myline, __ATOMIC_RELAXED,
                                     __HIP_MEMORY_SCOPE_AGENT) < gen)
                __builtin_amdgcn_s_sleep(2);
        }
        __syncthreads();
    }
    asm volatile("" ::: "memory");
}

// proj[b][s][k] = sum_h W_a[k][h] * enc[s][b][h]   (+ resets barrier state)
__global__ __launch_bounds__(256) void k_proj(const float* __restrict__ W_a,
                                              const float* __restrict__ enc,
                                              float* __restrict__ proj,
                                              unsigned int* __restrict__ bar) {
    if (blockIdx.x == 0 && blockIdx.y == 0 && blockIdx.z == 0) {
        bar[threadIdx.x * SLOT_PAD] = 0u;                       // arrival slots
        if (threadIdx.x < GO_LINES)
            bar[(NBLK + threadIdx.x) * SLOT_PAD] = 0u;          // go lines
    }
    int k = blockIdx.x * 256 + threadIdx.x;
    int s0 = blockIdx.y * 8;
    int b = blockIdx.z;
    __shared__ float se[8][Hc];
    for (int i = threadIdx.x; i < 8 * Hc; i += 256) {
        int ss = i >> 9, hh = i & (Hc - 1);
        se[ss][hh] = enc[((size_t)(s0 + ss) * Bc + b) * Hc + hh];
    }
    __syncthreads();
    const float* wr = W_a + (size_t)k * Hc;
    float acc[8];
#pragma unroll
    for (int ss = 0; ss < 8; ++ss) acc[ss] = 0.0f;
    for (int h = 0; h < Hc; h += 4) {
        float4 w = *(const float4*)(wr + h);
#pragma unroll
        for (int ss = 0; ss < 8; ++ss) {
            acc[ss] = fmaf(w.x, se[ss][h + 0], acc[ss]);
            acc[ss] = fmaf(w.y, se[ss][h + 1], acc[ss]);
            acc[ss] = fmaf(w.z, se[ss][h + 2], acc[ss]);
            acc[ss] = fmaf(w.w, se[ss][h + 3], acc[ss]);
        }
    }
#pragma unroll
    for (int ss = 0; ss < 8; ++ss)
        proj[((size_t)b * Sc + s0 + ss) * Hc + k] = acc[ss];
}

// Persistent decode loop, 3 barriers/step:
//  phase 1 (all 256 blocks): gates GEMM + LSTM        == k_step1 chains
//  phase 2/3 (blocks 0..31): score+softmax+ctx->ctxN  == k_score/k_ctx chains
//  phase 4 (all 256 blocks): Wc GEMV, 2 fixed W_c rows/block, 4 lanes/output
//                            (a0..a3 sub-chains + xor-shuffle == k_wc chain)
// Each block re-reads the SAME weight rows every step -> per-XCD working set
// < 4MB L2 -> weights fetched from HBM once, not 31x (verified: FETCH 73MB).
__global__ __launch_bounds__(256) void k_loop(
    const int* __restrict__ tgt, const int* __restrict__ len_src,
    const float* __restrict__ enc, const float* __restrict__ h0,
    const float* __restrict__ c0, const float* __restrict__ emb,
    const float* __restrict__ W_ih, const float* __restrict__ W_hh,
    const float* __restrict__ b_ih, const float* __restrict__ b_hh,
    const float* __restrict__ proj, const float* __restrict__ W_c,
    const float* __restrict__ b_c,
    float* __restrict__ h_all, float* __restrict__ cbuf,
    float* __restrict__ ah_all, float* __restrict__ ctx_all,
    unsigned int* __restrict__ bar) {
    int blk = blockIdx.x, tid = threadIdx.x;
    unsigned int* slots = bar;
    unsigned int* go = bar + NBLK * SLOT_PAD;
    unsigned int gen = 0;

    // prologue == k_init (write-through: read cross-XCD after the barrier)
    {
        int i = blk * 256 + tid;
        if (i < BH) {
            stg(&h_all[i], h0[i]);
            stg(&cbuf[i], c0[i]);
            stg(&ah_all[i], 0.0f);
        }
    }
    gbar(slots, go, ++gen);

    __shared__ float sg[2][4][32];
    __shared__ __align__(16) float sh[Hc];    // h2 for this batch (blocks<32)
    __shared__ float ss[Sc];
    __shared__ float sal[Sc];

    for (int t = 0; t < Tc - 1; ++t) {
        const float* hP = h_all + (size_t)t * BH;
        float*       hN = h_all + (size_t)(t + 1) * BH;
        const float* aP = ah_all + (size_t)t * BH;
        float*       aN = ah_all + (size_t)(t + 1) * BH;
        float*       ctxN = ctx_all + (size_t)t * BH;

        // ---------------- phase 1: k_step1 (all 256 blocks) ----------------
        {
            int b  = tid & 31;
            int q  = (tid >> 5) & 3;
            int hl = tid >> 7;
            int h  = blk * 2 + hl;
            int j  = q * Hc + h;
            int w  = tgt[b * Tc + t];
            const float* x  = emb + (size_t)w * Ec;
            const float* wi = W_ih + (size_t)j * (Ec + Hc);
            const float* wh = W_hh + (size_t)j * Hc;
            const float* ap = aP + b * Hc;
            const float* hp = hP + b * Hc;
            float a0 = 0.f, a1 = 0.f, a2 = 0.f, a3 = 0.f;
            for (int e = 0; e < Ec; e += 16) {
                a0 += dot4(x + e, wi + e);
                a1 += dot4(x + e + 4, wi + e + 4);
                a2 += dot4(x + e + 8, wi + e + 8);
                a3 += dot4(x + e + 12, wi + e + 12);
            }
            for (int k = 0; k < Hc; k += 16) {
                a0 += dot4(ap + k, wi + Ec + k);
                a1 += dot4(ap + k + 4, wi + Ec + k + 4);
                a2 += dot4(ap + k + 8, wi + Ec + k + 8);
                a3 += dot4(ap + k + 12, wi + Ec + k + 12);
            }
            for (int k = 0; k < Hc; k += 16) {
                a0 += dot4(hp + k, wh + k);
                a1 += dot4(hp + k + 4, wh + k + 4);
                a2 += dot4(hp + k + 8, wh + k + 8);
                a3 += dot4(hp + k + 12, wh + k + 12);
            }
            float acc = b_ih[j] + b_hh[j] + ((a0 + a1) + (a2 + a3));
            sg[hl][q][b] = acc;
            __syncthreads();
            if (q == 0) {
                float iv = sigf(sg[hl][0][b]);
                float fv = sigf(sg[hl][1][b]);
                float gv = tanhf(sg[hl][2][b]);
                float ov = sigf(sg[hl][3][b]);
                int idx = b * Hc + h;
                float c2 = fv * cbuf[idx] + iv * gv;
                float h2v = ov * tanhf(c2);
                cbuf[idx] = c2;        // same-thread read/write only: cacheable
                stg(&hN[idx], h2v);    // crosses barrier: write-through
            }
        }
        gbar(slots, go, ++gen);

        // --------- phase 2/3: k_score + k_ctx (blocks 0..31, b=blk) ---------
        if (blk < Bc) {
            int b = blk;
            for (int k = tid; k < Hc; k += 256) sh[k] = hN[b * Hc + k];
            __syncthreads();
            // scores (k_score chain)
            {
                int s = tid >> 2, r = tid & 3;
                const float* pr = proj + ((size_t)b * Sc + s) * Hc + r * 128;
                const float* hh = sh + r * 128;
                float p0 = 0.f, p1 = 0.f;
                for (int k = 0; k < 128; k += 8) {
                    p0 += dot4(hh + k, pr + k);
                    p1 += dot4(hh + k + 4, pr + k + 4);
                }
                float p = p0 + p1;
                p += __shfl_xor(p, 1);
                p += __shfl_xor(p, 2);
                if (r == 0) ss[s] = p;
            }
            __syncthreads();
            // masked softmax (k_score chain), lanes 0..63 of wave 0
            if (tid < Sc) {
                int len = len_src[b];
                float sc = (tid < len) ? ss[tid] : NEGC;
                float mx = sc;
#pragma unroll
                for (int m = 32; m >= 1; m >>= 1) mx = fmaxf(mx, __shfl_xor(mx, m));
                float p = expf(sc - mx);
                float sum = p;
#pragma unroll
                for (int m = 32; m >= 1; m >>= 1) sum += __shfl_xor(sum, m);
                sal[tid] = p / sum;
            }
            __syncthreads();
            // ctx (k_ctx chain): per h, two 32-long serial chains + one add
#pragma unroll
            for (int rep = 0; rep < 2; ++rep) {
                int h = tid + rep * 256;
                float accA = 0.0f, accB = 0.0f;
                for (int s = 0; s < 32; ++s)
                    accA = fmaf(sal[s], enc[((size_t)s * Bc + b) * Hc + h], accA);
                for (int s = 32; s < 64; ++s)
                    accB = fmaf(sal[s], enc[((size_t)s * Bc + b) * Hc + h], accB);
                stg(&ctxN[b * Hc + h], accA + accB);
            }
        }
        gbar(slots, go, ++gen);

        // ------------- phase 4: Wc GEMV (all 256 blocks) -------------
        // block owns W_c rows {2*blk, 2*blk+1} (same rows every step -> L2-hit).
        // 4 lanes per output compute the k_wc a0..a3 sub-chains; combine
        // ((a0+a1)+(a2+a3)) via xor-shuffles (fp add is bitwise commutative).
        {
            int r   = tid & 3;          // sub-chain index 0..3
            int out = tid >> 2;         // 0..63
            int b   = out >> 1;
            int kl  = out & 1;
            int k   = blk * 2 + kl;
            const float* wc  = W_c + (size_t)k * (2 * Hc) + 4 * r;
            const float* wc2 = wc + Hc;
            const float* hp  = hN + b * Hc + 4 * r;
            const float* cp  = ctxN + b * Hc + 4 * r;
            float ar = 0.f;
            for (int j = 0; j < Hc; j += 16)
                ar += dot4(hp + j, wc + j);
            for (int j = 0; j < Hc; j += 16)
                ar += dot4(cp + j, wc2 + j);
            float v01 = ar + __shfl_xor(ar, 1);   // (a0+a1) on lanes 0/1 pairs
            float v   = v01 + __shfl_xor(v01, 2); // ((a0+a1)+(a2+a3))
            if (r == 0)
                stg(&aN[b * Hc + k], tanhf(b_c[k] + v));
        }
        gbar(slots, go, ++gen);
    }
}

// Batched logits GEMM: C[m][n] = A[m][:] . W_o[n][:] + b_o[n]
__global__ __launch_bounds__(256) void k_biglogits(const float* __restrict__ A,
                                                   const float* __restrict__ W_o,
                                                   const float* __restrict__ b_o,
                                                   float* __restrict__ out) {
    __shared__ float At[32][128];
    __shared__ float Bt[32][128];
    int tid = threadIdx.x;
    int n_base = blockIdx.x * 128;
    int m_base = blockIdx.y * 128;
    int tn = tid & 15, tm = tid >> 4;

    float acc[2][4][2][4];
#pragma unroll
    for (int mg = 0; mg < 2; ++mg)
#pragma unroll
        for (int mi = 0; mi < 4; ++mi)
#pragma unroll
            for (int ng = 0; ng < 2; ++ng)
#pragma unroll
                for (int ni = 0; ni < 4; ++ni) acc[mg][mi][ng][ni] = 0.0f;

    int srow = tid >> 1;
    int koff = (tid & 1) * 16;
    int gm = m_base + srow;
    const float* arow = A + (size_t)gm * Hc + koff;
    const float* brow = W_o + (size_t)(n_base + srow) * Hc + koff;

    for (int kc = 0; kc < Hc; kc += 32) {
        float av[16], bv[16];
#pragma unroll
        for (int i = 0; i < 4; ++i) {
            float4 t4 = (gm < Mtot) ? *(const float4*)(arow + kc + i * 4)
                                    : make_float4(0.f, 0.f, 0.f, 0.f);
            av[i * 4 + 0] = t4.x; av[i * 4 + 1] = t4.y; av[i * 4 + 2] = t4.z; av[i * 4 + 3] = t4.w;
            float4 u4 = *(const float4*)(brow + kc + i * 4);
            bv[i * 4 + 0] = u4.x; bv[i * 4 + 1] = u4.y; bv[i * 4 + 2] = u4.z; bv[i * 4 + 3] = u4.w;
        }
        __syncthreads();
#pragma unroll
        for (int i = 0; i < 16; ++i) {
            At[koff + i][srow] = av[i];
            Bt[koff + i][srow] = bv[i];
        }
        __syncthreads();
#pragma unroll
        for (int k = 0; k < 32; ++k) {
            float4 a0 = *(const float4*)&At[k][tm * 4];
            float4 a1 = *(const float4*)&At[k][64 + tm * 4];
            float4 b0 = *(const float4*)&Bt[k][tn * 4];
            float4 b1 = *(const float4*)&Bt[k][64 + tn * 4];
            float am[2][4] = {{a0.x, a0.y, a0.z, a0.w}, {a1.x, a1.y, a1.z, a1.w}};
            float bn[2][4] = {{b0.x, b0.y, b0.z, b0.w}, {b1.x, b1.y, b1.z, b1.w}};
#pragma unroll
            for (int mg = 0; mg < 2; ++mg)
#pragma unroll
                for (int mi = 0; mi < 4; ++mi)
#pragma unroll
                    for (int ng = 0; ng < 2; ++ng)
#pragma unroll
                        for (int ni = 0; ni < 4; ++ni)
                            acc[mg][mi][ng][ni] = fmaf(am[mg][mi], bn[ng][ni], acc[mg][mi][ng][ni]);
        }
        __syncthreads();
    }

#pragma unroll
    for (int ng = 0; ng < 2; ++ng) {
        int n = n_base + ng * 64 + tn * 4;
        float4 bo = *(const float4*)(b_o + n);
#pragma unroll
        for (int mg = 0; mg < 2; ++mg)
#pragma unroll
            for (int mi = 0; mi < 4; ++mi) {
                int m = m_base + mg * 64 + tm * 4 + mi;
                if (m < Mtot) {
                    float4 v;
                    v.x = acc[mg][mi][ng][0] + bo.x;
                    v.y = acc[mg][mi][ng][1] + bo.y;
                    v.z = acc[mg][mi][ng][2] + bo.z;
                    v.w = acc[mg][mi][ng][3] + bo.w;
                    *(float4*)(out + (size_t)m * Vc + n) = v;
                }
            }
    }
}

// Per row m: argmax (first tiebreak) + logsumexp, then subtract in place; words out.
__global__ __launch_bounds__(256) void k_reduce_norm(float* __restrict__ out,
                                                     float* __restrict__ words) {
    int m = blockIdx.x, tid = threadIdx.x;
    float* row = out + (size_t)m * Vc;
    float mx = -INFINITY;
    int mi = 0;
    for (int v = tid; v < Vc; v += 256) {
        float x = row[v];
        if (x > mx) { mx = x; mi = v; }
    }
    __shared__ float smx[256];
    __shared__ int smi[256];
    __shared__ float ssum[256];
    smx[tid] = mx; smi[tid] = mi;
    __syncthreads();
    for (int off = 128; off; off >>= 1) {
        if (tid < off) {
            float o = smx[tid + off]; int oi = smi[tid + off];
            if (o > smx[tid] || (o == smx[tid] && oi < smi[tid])) { smx[tid] = o; smi[tid] = oi; }
        }
        __syncthreads();
    }
    float gmx = smx[0];
    float s = 0.0f;
    for (int v = tid; v < Vc; v += 256) s += expf(row[v] - gmx);
    ssum[tid] = s;
    __syncthreads();
    for (int off = 128; off; off >>= 1) {
        if (tid < off) ssum[tid] += ssum[tid + off];
        __syncthreads();
    }
    float lse = gmx + logf(ssum[0]);
    __syncthreads();
    for (int v = tid; v < Vc; v += 256) row[v] -= lse;
    if (tid == 0) words[m] = (float)smi[0];
}

extern "C" void kernel_launch(void* const* d_in, const int* in_sizes, int n_in,
                              void* d_out, int out_size, void* d_ws, size_t ws_size,
                              hipStream_t stream) {
    const int*   tgt     = (const int*)d_in[0];
    const int*   len_src = (const int*)d_in[1];
    const float* enc     = (const float*)d_in[2];
    const float* h0      = (const float*)d_in[3];
    const float* c0      = (const float*)d_in[4];
    const float* emb     = (const float*)d_in[5];
    const float* W_ih    = (const float*)d_in[6];
    const float* W_hh    = (const float*)d_in[7];
    const float* b_ih    = (const float*)d_in[8];
    const float* b_hh    = (const float*)d_in[9];
    const float* W_a     = (const float*)d_in[10];
    const float* W_c     = (const float*)d_in[11];
    const float* b_c     = (const float*)d_in[12];
    const float* W_o     = (const float*)d_in[13];
    const float* b_o     = (const float*)d_in[14];

    float* out = (float*)d_out;
    float* ws = (float*)d_ws;

    float* proj    = ws;                             // B*S*H = 1,048,576
    float* h_all   = proj + (size_t)Bc * Sc * Hc;    // 32 * BH (write-once slots)
    float* cbuf    = h_all + 32 * (size_t)BH;        // BH (same-thread in-place)
    float* ah_all  = cbuf + BH;                      // 32 * BH (slot0 = zeros)
    float* ctx_all = ah_all + 32 * (size_t)BH;       // 31 * BH (write-once slots)
    unsigned int* bar = (unsigned int*)(ctx_all + 31 * (size_t)BH);
    float* out_words = out + (size_t)(Tc - 1) * Bc * Vc;

    {
        dim3 g(Hc / 256, Sc / 8, Bc);
        k_proj<<<g, 256, 0, stream>>>(W_a, enc, proj, bar);
    }

    k_loop<<<NBLK, 256, 0, stream>>>(tgt, len_src, enc, h0, c0, emb,
                                     W_ih, W_hh, b_ih, b_hh, proj, W_c, b_c,
                                     h_all, cbuf, ah_all, ctx_all, bar);

    {
        dim3 g(Vc / 128, (Mtot + 127) / 128);    // 250 x 8
        k_biglogits<<<g, 256, 0, stream>>>(ah_all + BH, W_o, b_o, out);
    }
    k_reduce_norm<<<Mtot, 256, 0, stream>>>(out, out_words);
}